// Round 9
// baseline (331.300 us; speedup 1.0000x reference)
//
#include <hip/hip_runtime.h>
#include <hip/hip_fp16.h>

// GCN 2-layer, CSR-gather formulation, fp16 storage / fp32 math, MFMA GEMMs.
//   y = half(x * dinv)                     (fused into k_fillb)
//   aggX[c] = half( dinv[c] * (y[c] + sum_{r in in(c)} y[r]) )
//   h1 = half( relu(aggX @ W1 + b1) )      [MFMA f16, fp32 acc]
//   z  = half( (h1 @ W2) * dinv )          [MFMA f16, fp32 acc]
//   out[c] = fp32( dinv[c] * (z[c] + sum z[r]) + b2 )
// CSR build: fully deterministic, NO global atomics anywhere (rounds 1/3/4/7
// lesson: random global atomics/stores cost a 32-64B HBM line each; every
// scatter target region must be owned by ONE block so L2 merges full lines).
// Gathers: wave per node, lane-groups load 16B row-chunks so one load
// instruction covers 4 (width-128) or 8 (width-64) edges; fp32 butterfly
// reduction across groups (round-8 lesson: gathers were issue-limited,
// VALUBusy 35% / HBM 42%).

constexpr int NN = 100000;   // nodes
constexpr int NE = 1600000;  // edges
constexpr int BSH = 7;       // 128 nodes per bucket
constexpr int NB = (NN + 127) >> BSH;  // 782 buckets
constexpr int NBLK = 256;    // binning blocks
constexpr int EPB = NE / NBLK;  // 6250 edges per block (exact)
constexpr int TSTR = 784;    // table row stride (ints)

typedef _Float16 f16x8 __attribute__((ext_vector_type(8)));
typedef float f32x4 __attribute__((ext_vector_type(4)));

// ------------- per-(block,bucket) histogram (LDS atomics only) ---------------
__global__ __launch_bounds__(256) void k_hist(const int* __restrict__ cols,
                                              int* __restrict__ table) {
  __shared__ int cnt[NB];
  for (int i = threadIdx.x; i < NB; i += 256) cnt[i] = 0;
  __syncthreads();
  int base = blockIdx.x * EPB;
  for (int i = threadIdx.x; i < EPB; i += 256)
    atomicAdd(&cnt[cols[base + i] >> BSH], 1);
  __syncthreads();
  for (int i = threadIdx.x; i < NB; i += 256)
    table[blockIdx.x * TSTR + i] = cnt[i];
}

// ------- scan table columns over blocks: startOff + bucket totals ------------
__global__ __launch_bounds__(256) void k_scanT(const int* __restrict__ table,
                                               int* __restrict__ startOff,
                                               int* __restrict__ btot) {
  __shared__ int s[256];
  int b = blockIdx.x, t = threadIdx.x;
  int v = table[t * TSTR + b];
  s[t] = v;
  __syncthreads();
  for (int off = 1; off < 256; off <<= 1) {
    int tmp = (t >= off) ? s[t - off] : 0;
    __syncthreads();
    s[t] += tmp;
    __syncthreads();
  }
  startOff[t * TSTR + b] = s[t] - v;
  if (t == 255) btot[b] = s[t];
}

// ------- exclusive scan of 782 bucket totals -> bucketBase (1 block) ---------
__global__ __launch_bounds__(256) void k_scanBkt(const int* __restrict__ btot,
                                                 int* __restrict__ bucketBase) {
  __shared__ int s[256];
  int t = threadIdx.x;
  int base = t * 4;
  int d0 = (base + 0 < NB) ? btot[base + 0] : 0;
  int d1 = (base + 1 < NB) ? btot[base + 1] : 0;
  int d2 = (base + 2 < NB) ? btot[base + 2] : 0;
  int d3 = (base + 3 < NB) ? btot[base + 3] : 0;
  int tsum = d0 + d1 + d2 + d3;
  s[t] = tsum;
  __syncthreads();
  for (int off = 1; off < 256; off <<= 1) {
    int tmp = (t >= off) ? s[t - off] : 0;
    __syncthreads();
    s[t] += tmp;
    __syncthreads();
  }
  int ex = s[t] - tsum;
  if (base + 0 < NB) bucketBase[base + 0] = ex;
  if (base + 1 < NB) bucketBase[base + 1] = ex + d0;
  if (base + 2 < NB) bucketBase[base + 2] = ex + d0 + d1;
  if (base + 3 < NB) bucketBase[base + 3] = ex + d0 + d1 + d2;
}

// ------- scatter edges into bucket-grouped array (LDS counters only) ---------
__global__ __launch_bounds__(256) void k_scat(const int* __restrict__ rows,
                                              const int* __restrict__ cols,
                                              const int* __restrict__ startOff,
                                              const int* __restrict__ bucketBase,
                                              unsigned* __restrict__ binned) {
  __shared__ int scnt[NB];
  int blk = blockIdx.x;
  for (int i = threadIdx.x; i < NB; i += 256)
    scnt[i] = bucketBase[i] + startOff[blk * TSTR + i];
  __syncthreads();
  int base = blk * EPB;
  for (int i = threadIdx.x; i < EPB; i += 256) {
    int c = cols[base + i];
    int r = rows[base + i];
    int pos = atomicAdd(&scnt[c >> BSH], 1);
    binned[pos] = ((unsigned)r << BSH) | (unsigned)(c & 127);
  }
}

// --- per-bucket fill: deg/rowptr/dinv + node-grouped srcIdx + y conversion ---
// one block per bucket; block exclusively owns all its output ranges
__global__ __launch_bounds__(256) void k_fillb(const unsigned* __restrict__ binned,
                                               const int* __restrict__ bucketBase,
                                               const int* __restrict__ btot,
                                               const float4* __restrict__ x4,
                                               int* __restrict__ rowptr,
                                               int* __restrict__ deg,
                                               float* __restrict__ dinv,
                                               int* __restrict__ srcIdx,
                                               float2* __restrict__ y8) {
  __shared__ int cnt[128];
  __shared__ int sc[128];
  __shared__ int rp[128];
  __shared__ float dnv[128];
  int b = blockIdx.x;
  int nb0 = b << BSH;
  int nn = min(128, NN - nb0);
  int tid = threadIdx.x;
  if (tid < 128) cnt[tid] = 0;
  __syncthreads();
  int ebeg = bucketBase[b];
  int eend = ebeg + btot[b];
  // pass 1: local degree count
  for (int p = ebeg + tid; p < eend; p += 256)
    atomicAdd(&cnt[binned[p] & 127], 1);
  __syncthreads();
  // block scan of the 128 local degrees
  int v = (tid < 128) ? cnt[tid] : 0;
  if (tid < 128) sc[tid] = v;
  __syncthreads();
  for (int off = 1; off < 128; off <<= 1) {
    int tmp = (tid < 128 && tid >= off) ? sc[tid - off] : 0;
    __syncthreads();
    if (tid < 128) sc[tid] += tmp;
    __syncthreads();
  }
  if (tid < 128) {
    int ex = sc[tid] - v;
    rp[tid] = ebeg + ex;
    float dv = rsqrtf((float)v + 1.0f);
    dnv[tid] = dv;
    if (tid < nn) {
      rowptr[nb0 + tid] = ebeg + ex;
      deg[nb0 + tid] = v;
      dinv[nb0 + tid] = dv;
    }
    cnt[tid] = 0;
  }
  __syncthreads();
  // pass 2: scatter srcIdx (node-grouped, contiguous per bucket)
  for (int p = ebeg + tid; p < eend; p += 256) {
    unsigned pk = binned[p];
    int cl = pk & 127;
    int local = atomicAdd(&cnt[cl], 1);
    srcIdx[rp[cl] + local] = (int)(pk >> BSH);
  }
  // y-phase: y = half(x * dinv) for this bucket's nodes (dinv from LDS)
  for (int i = tid; i < nn * 32; i += 256) {
    int n = i >> 5, j = i & 31;
    float s = dnv[n];
    float4 vv = x4[(size_t)(nb0 + n) * 32 + j];
    union { __half2 h[2]; float2 f; } u;
    u.h[0] = __floats2half2_rn(vv.x * s, vv.y * s);
    u.h[1] = __floats2half2_rn(vv.z * s, vv.w * s);
    y8[(size_t)(nb0 + n) * 32 + j] = u.f;
  }
}

// ------------- weight convert+transpose (both layers, one launch) ------------
__global__ __launch_bounds__(256) void k_wt(const float* __restrict__ W1,
                                            const float* __restrict__ W2,
                                            __half* __restrict__ Wt1,
                                            __half* __restrict__ Wt2) {
  int i = blockIdx.x * 256 + threadIdx.x;
  if (i < 128 * 128) {
    int k = i >> 7, n = i & 127;
    Wt1[n * 128 + k] = __float2half(W1[i]);
  } else if (i < 128 * 128 + 128 * 64) {
    int j = i - 128 * 128;
    int k = j >> 6, n = j & 63;
    Wt2[n * 128 + k] = __float2half(W2[j]);
  }
}

// ------- gather-aggregate, width 128: wave/node, 4 groups x 16 lanes x 16B ---
__global__ __launch_bounds__(256) void k_gath1(const __half2* __restrict__ y2,
                                               const int* __restrict__ rowptr,
                                               const int* __restrict__ deg,
                                               const int* __restrict__ srcIdx,
                                               const float* __restrict__ dinv,
                                               __half2* __restrict__ agg) {
  int node = blockIdx.x * 4 + (threadIdx.x >> 6);
  int lane = threadIdx.x & 63;
  int g = lane >> 4, m = lane & 15;
  int d = deg[node];
  int p = rowptr[node];
  float acc[8];
#pragma unroll
  for (int j = 0; j < 8; j++) acc[j] = 0.0f;

  for (int base = 0; base < d; base += 64) {
    int cnt = min(64, d - base);
    int my = srcIdx[min(p + base + lane, NE - 1)];
    int k = 0;
    for (; k + 8 <= cnt; k += 8) {  // 8 edges per iter, 2 x 16B loads/lane
      int s0 = __shfl(my, k + g);
      int s1 = __shfl(my, k + 4 + g);
      float4 f0 = *reinterpret_cast<const float4*>(y2 + (size_t)s0 * 64 + m * 4);
      float4 f1 = *reinterpret_cast<const float4*>(y2 + (size_t)s1 * 64 + m * 4);
      const __half2* h0 = reinterpret_cast<const __half2*>(&f0);
      const __half2* h1 = reinterpret_cast<const __half2*>(&f1);
#pragma unroll
      for (int q = 0; q < 4; q++) {
        float2 a = __half22float2(h0[q]);
        float2 bb = __half22float2(h1[q]);
        acc[2 * q] += a.x + bb.x;
        acc[2 * q + 1] += a.y + bb.y;
      }
    }
    for (; k < cnt; k += 4) {  // predicated tail, 4 edges per iter
      int e = k + g;
      int s0 = __shfl(my, min(e, cnt - 1));
      if (e < cnt) {
        float4 f0 = *reinterpret_cast<const float4*>(y2 + (size_t)s0 * 64 + m * 4);
        const __half2* h0 = reinterpret_cast<const __half2*>(&f0);
#pragma unroll
        for (int q = 0; q < 4; q++) {
          float2 a = __half22float2(h0[q]);
          acc[2 * q] += a.x;
          acc[2 * q + 1] += a.y;
        }
      }
    }
  }
  // fold the 4 lane-groups (lane bits 4,5)
#pragma unroll
  for (int j = 0; j < 8; j++) {
    acc[j] += __shfl_xor(acc[j], 16);
    acc[j] += __shfl_xor(acc[j], 32);
  }
  if (g == 0) {  // self-loop + scale + 256B row store by 16 lanes
    float4 fs = *reinterpret_cast<const float4*>(y2 + (size_t)node * 64 + m * 4);
    const __half2* hs = reinterpret_cast<const __half2*>(&fs);
    float sc = dinv[node];
    union { __half2 h[4]; float4 f; } o;
#pragma unroll
    for (int q = 0; q < 4; q++) {
      float2 a = __half22float2(hs[q]);
      o.h[q] = __floats2half2_rn((acc[2 * q] + a.x) * sc, (acc[2 * q + 1] + a.y) * sc);
    }
    *reinterpret_cast<float4*>(agg + (size_t)node * 64 + m * 4) = o.f;
  }
}

// ------- gather-aggregate, width 64: wave/node, 8 groups x 8 lanes x 16B -----
__global__ __launch_bounds__(256) void k_gath2(const __half2* __restrict__ z2,
                                               const int* __restrict__ rowptr,
                                               const int* __restrict__ deg,
                                               const int* __restrict__ srcIdx,
                                               const float* __restrict__ dinv,
                                               const float* __restrict__ b2,
                                               float* __restrict__ out) {
  int node = blockIdx.x * 4 + (threadIdx.x >> 6);
  int lane = threadIdx.x & 63;
  int g = lane >> 3, m = lane & 7;
  int d = deg[node];
  int p = rowptr[node];
  float acc[8];
#pragma unroll
  for (int j = 0; j < 8; j++) acc[j] = 0.0f;

  for (int base = 0; base < d; base += 64) {
    int cnt = min(64, d - base);
    int my = srcIdx[min(p + base + lane, NE - 1)];
    int k = 0;
    for (; k + 16 <= cnt; k += 16) {  // 16 edges per iter
      int s0 = __shfl(my, k + g);
      int s1 = __shfl(my, k + 8 + g);
      float4 f0 = *reinterpret_cast<const float4*>(z2 + (size_t)s0 * 32 + m * 4);
      float4 f1 = *reinterpret_cast<const float4*>(z2 + (size_t)s1 * 32 + m * 4);
      const __half2* h0 = reinterpret_cast<const __half2*>(&f0);
      const __half2* h1 = reinterpret_cast<const __half2*>(&f1);
#pragma unroll
      for (int q = 0; q < 4; q++) {
        float2 a = __half22float2(h0[q]);
        float2 bb = __half22float2(h1[q]);
        acc[2 * q] += a.x + bb.x;
        acc[2 * q + 1] += a.y + bb.y;
      }
    }
    for (; k < cnt; k += 8) {  // predicated tail, 8 edges per iter
      int e = k + g;
      int s0 = __shfl(my, min(e, cnt - 1));
      if (e < cnt) {
        float4 f0 = *reinterpret_cast<const float4*>(z2 + (size_t)s0 * 32 + m * 4);
        const __half2* h0 = reinterpret_cast<const __half2*>(&f0);
#pragma unroll
        for (int q = 0; q < 4; q++) {
          float2 a = __half22float2(h0[q]);
          acc[2 * q] += a.x;
          acc[2 * q + 1] += a.y;
        }
      }
    }
  }
  // fold the 8 lane-groups (lane bits 3,4,5)
#pragma unroll
  for (int j = 0; j < 8; j++) {
    acc[j] += __shfl_xor(acc[j], 8);
    acc[j] += __shfl_xor(acc[j], 16);
    acc[j] += __shfl_xor(acc[j], 32);
  }
  if (g == 0) {  // self-loop + scale + bias + 256B fp32 row store by 8 lanes
    float4 fs = *reinterpret_cast<const float4*>(z2 + (size_t)node * 32 + m * 4);
    const __half2* hs = reinterpret_cast<const __half2*>(&fs);
    float s = dinv[node];
    float4 bv0 = *reinterpret_cast<const float4*>(b2 + m * 8);
    float4 bv1 = *reinterpret_cast<const float4*>(b2 + m * 8 + 4);
    float2 a0 = __half22float2(hs[0]), a1 = __half22float2(hs[1]);
    float2 a2 = __half22float2(hs[2]), a3 = __half22float2(hs[3]);
    float4 o0 = make_float4((acc[0] + a0.x) * s + bv0.x, (acc[1] + a0.y) * s + bv0.y,
                            (acc[2] + a1.x) * s + bv0.z, (acc[3] + a1.y) * s + bv0.w);
    float4 o1 = make_float4((acc[4] + a2.x) * s + bv1.x, (acc[5] + a2.y) * s + bv1.y,
                            (acc[6] + a3.x) * s + bv1.z, (acc[7] + a3.y) * s + bv1.w);
    *reinterpret_cast<float4*>(out + (size_t)node * 64 + m * 8) = o0;
    *reinterpret_cast<float4*>(out + (size_t)node * 64 + m * 8 + 4) = o1;
  }
}

// ---- MFMA GEMM: C[M,BN] = A[M,128] @ W[128,BN], f16 in, fp32 acc, f16 out ---
template <int BN, bool BIASRELU, bool ROWSCALE>
__global__ __launch_bounds__(256) void k_gemmM(const __half* __restrict__ A,
                                               const __half* __restrict__ Wt,
                                               const float* __restrict__ bias,
                                               const float* __restrict__ rowscale,
                                               __half* __restrict__ C, int M) {
  constexpr int NT = BN / 16;  // 8 or 4 col tiles per wave
  __shared__ __half tile[4][16][BN + 8];
  const int w = threadIdx.x >> 6, l = threadIdx.x & 63;
  const int quad = l >> 4, m = l & 15;
  const int rowTop = blockIdx.x * 64 + w * 16;

  f32x4 acc[NT];
#pragma unroll
  for (int t = 0; t < NT; t++) {
    float bv = BIASRELU ? bias[t * 16 + m] : 0.0f;
    acc[t] = (f32x4){bv, bv, bv, bv};
  }

  int arow = rowTop + m;
  if (arow >= M) arow = M - 1;  // clamp: garbage rows computed but not stored
  const __half* ap = A + (size_t)arow * 128 + quad * 8;

#pragma unroll
  for (int kc = 0; kc < 128; kc += 32) {
    f16x8 a = *reinterpret_cast<const f16x8*>(ap + kc);
#pragma unroll
    for (int t = 0; t < NT; t++) {
      f16x8 b = *reinterpret_cast<const f16x8*>(
          Wt + (size_t)(t * 16 + m) * 128 + kc + quad * 8);
      acc[t] = __builtin_amdgcn_mfma_f32_16x16x32_f16(a, b, acc[t], 0, 0, 0);
    }
  }

  float rs[4];
  if constexpr (ROWSCALE) {
#pragma unroll
    for (int i = 0; i < 4; i++) {
      int r = rowTop + quad * 4 + i;
      rs[i] = rowscale[r < M ? r : M - 1];
    }
  }
#pragma unroll
  for (int t = 0; t < NT; t++)
#pragma unroll
    for (int i = 0; i < 4; i++) {
      float v = acc[t][i];
      if constexpr (BIASRELU) v = fmaxf(v, 0.0f);
      if constexpr (ROWSCALE) v *= rs[i];
      tile[w][quad * 4 + i][t * 16 + m] = __float2half(v);
    }
  __syncthreads();

  constexpr int CH = 16 * BN / 8;
#pragma unroll
  for (int rep = 0; rep < CH / 64; rep++) {
    int idx = rep * 64 + l;
    int r = idx / (BN / 8), cc = idx % (BN / 8);
    int grow = rowTop + r;
    if (grow < M)
      *reinterpret_cast<float4*>(C + (size_t)grow * BN + cc * 8) =
          *reinterpret_cast<const float4*>(&tile[w][r][cc * 8]);
  }
}

extern "C" void kernel_launch(void* const* d_in, const int* in_sizes, int n_in,
                              void* d_out, int out_size, void* d_ws, size_t ws_size,
                              hipStream_t stream) {
  const float* x  = (const float*)d_in[0];
  const int*   ei = (const int*)d_in[1];  // [2, NE] row-major
  const int* rows = ei;
  const int* cols = ei + NE;
  const float* W1 = (const float*)d_in[3];
  const float* b1 = (const float*)d_in[4];
  const float* W2 = (const float*)d_in[5];
  const float* b2 = (const float*)d_in[6];
  float* out = (float*)d_out;

  // ---- workspace carve (~90 MB) ----
  char* base = (char*)d_ws;
  constexpr size_t MB = 1 << 20;
  int*      deg       = (int*)(base + 0 * MB);
  int*      rowptr    = (int*)(base + 1 * MB);
  float*    dinv      = (float*)(base + 2 * MB);
  int*      btot      = (int*)(base + 3 * MB);                  // 3.2 KB
  int*      bucketBase= (int*)(base + 3 * MB + 16 * 1024);      // 3.2 KB
  __half*   Wt1       = (__half*)(base + 3 * MB + 64 * 1024);   // 32 KB
  __half*   Wt2       = (__half*)(base + 3 * MB + 128 * 1024);  // 16 KB
  int*      table     = (int*)(base + 4 * MB);   // 803 KB
  int*      startOff  = (int*)(base + 5 * MB);   // 803 KB
  unsigned* binned    = (unsigned*)(base + 6 * MB);   // 6.4 MB
  int*      srcIdx    = (int*)(base + 13 * MB);       // 6.4 MB
  __half2*  y         = (__half2*)(base + 20 * MB);   // 25.6 MB (reused for z)
  __half*   aggx      = (__half*)(base + 46 * MB);    // 25.6 MB
  __half*   h1        = (__half*)(base + 72 * MB);    // 25.6 MB
  __half2*  z         = (__half2*)(base + 20 * MB);   // 12.8 MB (y dead)

  k_wt<<<96, 256, 0, stream>>>(W1, W2, Wt1, Wt2);
  k_hist<<<NBLK, 256, 0, stream>>>(cols, table);
  k_scanT<<<NB, 256, 0, stream>>>(table, startOff, btot);
  k_scanBkt<<<1, 256, 0, stream>>>(btot, bucketBase);
  k_scat<<<NBLK, 256, 0, stream>>>(rows, cols, startOff, bucketBase, binned);
  k_fillb<<<NB, 256, 0, stream>>>(binned, bucketBase, btot, (const float4*)x,
                                  rowptr, deg, dinv, srcIdx, (float2*)y);
  k_gath1<<<NN / 4, 256, 0, stream>>>(y, rowptr, deg, srcIdx, dinv,
                                      (__half2*)aggx);
  k_gemmM<128, true, false><<<(NN + 63) / 64, 256, 0, stream>>>(
      aggx, Wt1, b1, nullptr, h1, NN);
  k_gemmM<64, false, true><<<(NN + 63) / 64, 256, 0, stream>>>(
      h1, Wt2, nullptr, dinv, (__half*)z, NN);
  k_gath2<<<NN / 4, 256, 0, stream>>>(z, rowptr, deg, srcIdx, dinv, b2, out);
}